// Round 10
// baseline (344.040 us; speedup 1.0000x reference)
//
#include <hip/hip_runtime.h>
#include <stdint.h>

// sign-binarized 3x3 conv via i8 implicit-GEMM on MFMA.
// N=32, Cin=Cout=256, H=W=56, K=3, pad=1, stride=1.
// sign(x),sign(M) in {+1,-1} as i8; zero halo => padding contributes 0 (exact).
//
// ws layout:
//   xb8 : i8 activations NHWC with halo, [N][58][58][256]   (27,557,888 B)
//   wb8 : i8 weights [tap][co][ci]                           (589,824 B)

#define CIN  256
#define COUT 256
#define HH   56
#define WW   56
#define NN   32
#define HP   58
#define HWI  (HH*WW)

typedef unsigned int u32;
typedef unsigned long long u64;
typedef int i32x4  __attribute__((ext_vector_type(4)));
typedef int i32x16 __attribute__((ext_vector_type(16)));

#define XB8_BYTES ((size_t)NN*HP*HP*CIN)     // 27,557,888
#define WB8_BYTES ((size_t)9*COUT*CIN)       // 589,824

// ---------------- pack weights: M (OIHW fp32) -> wb8[t][co][ci] i8 ----------
__global__ __launch_bounds__(256) void pack_w8(const float* __restrict__ M,
                                               char* __restrict__ wb8) {
    int co = blockIdx.x, ci = threadIdx.x;
    const float* mp = M + ((size_t)co * CIN + ci) * 9;   // 9 taps contiguous
    #pragma unroll
    for (int t = 0; t < 9; ++t) {
        char s = (mp[t] >= 0.0f) ? (char)1 : (char)-1;
        wb8[((size_t)t * COUT + co) * CIN + ci] = s;     // ci-coalesced stores
    }
}

// ---------------- pack activations: x (NCHW fp32) -> xb8 NHWC i8 + halo -----
// One block per (n, hr). LDS row tile [58 wc][264 pitch] i8, transposed out.
__global__ __launch_bounds__(256) void pack_x8(const float* __restrict__ x,
                                               char* __restrict__ xb8) {
    __shared__ char row[58 * 264];                 // 15312 B
    int bx   = blockIdx.x;
    int n    = bx / HP;
    int hr   = bx - n * HP;
    int tid  = threadIdx.x, lane = tid & 63, wv = tid >> 6;
    char* dst = xb8 + ((size_t)n * HP + hr) * HP * CIN;

    if (hr == 0 || hr == HP - 1) {                 // halo rows: zeros
        for (int o = tid * 16; o < HP * CIN; o += 256 * 16)
            *(int4*)(dst + o) = make_int4(0, 0, 0, 0);
        return;
    }
    for (int o = tid; o < 58 * 264 / 4; o += 256)  // zero LDS (covers halo cols)
        ((u32*)row)[o] = 0;
    __syncthreads();

    int h = hr - 1;
    if (lane < WW) {
        const float* xr = x + (((size_t)n * CIN + wv * 64) * HH + h) * WW + lane;
        #pragma unroll 4
        for (int c4 = 0; c4 < 16; ++c4) {          // 4 channels per packed u32
            u32 pk = 0;
            #pragma unroll
            for (int j = 0; j < 4; ++j) {
                float v = xr[(size_t)(c4 * 4 + j) * HWI];
                pk |= (u32)(unsigned char)(v >= 0.0f ? 1 : 0xFF) << (8 * j);
            }
            *(u32*)&row[(lane + 1) * 264 + wv * 64 + c4 * 4] = pk;  // 2-way bank ok
        }
    }
    __syncthreads();
    for (int o = tid * 8; o < HP * CIN; o += 256 * 8) {   // LDS -> global, coalesced
        int wc = o >> 8, ci = o & 255;
        *(u64*)(dst + o) = *(u64*)&row[wc * 264 + ci];
    }
}

// ---------------- conv: i8 implicit GEMM, 9 shifted taps --------------------
// M=co (A=weights), N=pixels (B=activations), K=ci. mfma_i32_32x32x32_i8.
// Block: 128 co x (4h x 64w = 256 pix), 4 waves; wave = 2 co-frag x 4 pix-frag.
// A_lds: activation tile rows h0-1..h0+4 x cols(-1..56) x 128ci chunk, slot-
// XOR-swizzled (slot^(col&7)) to cut the 128B-stride 32-way conflict to 4-way.
__global__ __launch_bounds__(256, 2) void conv_mfma(const char* __restrict__ xb8,
                                                    const char* __restrict__ wb8,
                                                    const float* __restrict__ alpha,
                                                    float* __restrict__ out) {
    __shared__ char A_lds[356 * 128];              // 348 cells + guard

    int tid  = threadIdx.x, lane = tid & 63, wave = tid >> 6;
    int l31  = lane & 31,  lhi  = lane >> 5;
    int mw   = wave >> 1,  nw   = wave & 1;
    int bx   = blockIdx.x;                         // n*14 + htile
    int n    = bx / 14;
    int h0   = (bx - n * 14) * 4;
    int co0  = blockIdx.y * 128;

    i32x16 acc[2][4] = {};                         // [co-frag][pix-frag]

    // per-lane weight base: co = co0 + mw*64 + mc*32 + l31 ; ci-lo = lhi*16
    const char* wbase = wb8 + ((size_t)(co0 + mw * 64 + l31)) * CIN + lhi * 16;
    const char* src   = xb8 + (((size_t)n * HP + h0) * HP) * CIN;  // rows h0..h0+5

    for (int cb = 0; cb < 2; ++cb) {               // 128-ci chunks
        if (cb) __syncthreads();
        // stage 348 cells x 128 B (global -> reg -> LDS, swizzled write)
        #pragma unroll
        for (int it = 0; it < 11; ++it) {
            int o = it * 4096 + tid * 16;
            if (o < 348 * 128) {
                int cell = o >> 7;
                int slot = (o >> 4) & 7;
                int col  = cell % 58;
                int4 v = *(const int4*)(src + (size_t)cell * 256 + cb * 128 + slot * 16);
                *(int4*)&A_lds[cell * 128 + ((slot ^ (col & 7)) << 4)] = v;
            }
        }
        __syncthreads();

        #pragma unroll
        for (int t = 0; t < 9; ++t) {
            int dh = t / 3 - 1, dw = t % 3 - 1;
            #pragma unroll
            for (int kk = 0; kk < 4; ++kk) {       // K=32 steps within chunk
                i32x4 wf[2];
                #pragma unroll
                for (int mc = 0; mc < 2; ++mc)
                    wf[mc] = *(const i32x4*)(wbase + (size_t)t * COUT * CIN
                                             + mc * 32 * CIN + cb * 128 + kk * 32);
                i32x4 af[4];
                #pragma unroll
                for (int pf = 0; pf < 4; ++pf) {
                    int hl   = nw * 2 + (pf >> 1);
                    int wl   = (pf & 1) * 32 + l31;
                    int col  = wl + 1 + dw;
                    int cell = (hl + 1 + dh) * 58 + col;
                    int slot = kk * 2 + lhi;
                    af[pf] = *(const i32x4*)&A_lds[cell * 128 + ((slot ^ (col & 7)) << 4)];
                }
                #pragma unroll
                for (int mc = 0; mc < 2; ++mc)
                    #pragma unroll
                    for (int pf = 0; pf < 4; ++pf)
                        acc[mc][pf] = __builtin_amdgcn_mfma_i32_32x32x32_i8(
                            wf[mc], af[pf], acc[mc][pf], 0, 0, 0);
            }
        }
    }

    // epilogue: D col = pixel (w-contiguous stores), row = co
    #pragma unroll
    for (int mc = 0; mc < 2; ++mc) {
        #pragma unroll
        for (int pf = 0; pf < 4; ++pf) {
            int hl = nw * 2 + (pf >> 1);
            int wg = (pf & 1) * 32 + l31;          // 0..63; >=56 is tile pad
            if (wg < WW) {
                int h = h0 + hl;
                #pragma unroll
                for (int q = 0; q < 16; ++q) {
                    int co = co0 + mw * 64 + mc * 32 + (q & 3) + 8 * (q >> 2) + 4 * lhi;
                    float v = (float)acc[mc][pf][q] * alpha[co];
                    __builtin_nontemporal_store(
                        v, out + ((size_t)n * COUT + co) * HWI + h * WW + wg);
                }
            }
        }
    }
}

extern "C" void kernel_launch(void* const* d_in, const int* in_sizes, int n_in,
                              void* d_out, int out_size, void* d_ws, size_t ws_size,
                              hipStream_t stream) {
    const float* x     = (const float*)d_in[0];
    const float* M     = (const float*)d_in[1];
    const float* alpha = (const float*)d_in[2];
    float* out = (float*)d_out;

    char* ws  = (char*)d_ws;
    char* xb8 = ws;
    char* wb8 = ws + XB8_BYTES;

    pack_w8<<<COUT, 256, 0, stream>>>(M, wb8);
    pack_x8<<<NN * HP, 256, 0, stream>>>(x, xb8);
    dim3 cgrid(NN * 14, 2);                        // 448 pixel-tiles x 2 co-splits
    conv_mfma<<<cgrid, 256, 0, stream>>>(xb8, wb8, alpha, out);
}